// Round 3
// baseline (227.078 us; speedup 1.0000x reference)
//
#include <hip/hip_runtime.h>

// SST forward for B=32, N=1048576 (fp32).
// Reference decomposes each row into L = N/2 pairs:
//   cA[k] = (x[2k] + x[2k+1]) * (1/sqrt(2))
//   cD[k] = (x[2k] - x[2k+1]) * (1/sqrt(2))
// d[k] = sign-code: (cD<0) - (cA<0)  in {-1,0,+1}  (from angle-diff clip)
// out[b,k,1] = cD[k]
// out[b,k,0] = cA[k]   if d[k]==0, or k==0 && d[k]==-1 (clip), or k==L-1 && d[k]==+1 (clip)
//            + cA[k-1] if k>=1   && d[k-1]==+1
//            + cA[k+1] if k<=L-2 && d[k+1]==-1
// out[b,k,0:2] lives at the same flat offset as x[b,2k:2k+2] -> pointwise + halo.

#define BB 32
#define NN 1048576
#define LL (NN / 2)        // 524288 pairs per row
#define CPR (LL / 2)       // 262144 float4-chunks (2 pairs) per row; = 2^18
#define NCHUNK (BB * CPR)  // 8388608 total chunks

__global__ __launch_bounds__(256) void sst_kernel(const float* __restrict__ x,
                                                  float* __restrict__ out) {
    const float s = 0.70710678118654752440f;
    const int stride = gridDim.x * blockDim.x;
    for (int c = blockIdx.x * blockDim.x + threadIdx.x; c < NCHUNK; c += stride) {
        const int row = c >> 18;             // c / CPR
        const int cw  = c & (CPR - 1);       // c % CPR
        const int k0  = cw << 1;             // first pair index of this chunk
        const float* __restrict__ rx = x   + (size_t)row * NN;
        float*       __restrict__ ro = out + (size_t)row * NN;

        // main 2 pairs (16B aligned: k0*2 is a multiple of 4)
        const float4 m = *(const float4*)(rx + (size_t)(k0 << 1));

        const bool hasL = (k0 > 0);
        const bool hasR = (k0 + 2 < LL);
        const float2 lp = hasL ? *(const float2*)(rx + (size_t)(k0 << 1) - 2)
                               : make_float2(0.f, 0.f);
        const float2 rp = hasR ? *(const float2*)(rx + (size_t)(k0 << 1) + 4)
                               : make_float2(0.f, 0.f);

        const float cAL = (lp.x + lp.y) * s, cDL = (lp.x - lp.y) * s;
        const float cA0 = (m.x + m.y) * s,  cD0 = (m.x - m.y) * s;
        const float cA1 = (m.z + m.w) * s,  cD1 = (m.z - m.w) * s;
        const float cAR = (rp.x + rp.y) * s, cDR = (rp.x - rp.y) * s;

        const int dL = (cDL < 0.f) - (cAL < 0.f);
        const int d0 = (cD0 < 0.f) - (cA0 < 0.f);
        const int d1 = (cD1 < 0.f) - (cA1 < 0.f);
        const int dR = (cDR < 0.f) - (cAR < 0.f);

        // k0 is even so k0 == LL-1 never; k0+1 is odd so k0+1 == 0 never.
        const bool keep0 = (d0 == 0) || (k0 == 0 && d0 == -1);
        const bool keep1 = (d1 == 0) || ((k0 + 1 == LL - 1) && d1 == 1);

        const float A0 = (keep0 ? cA0 : 0.f)
                       + ((hasL && dL == 1) ? cAL : 0.f)
                       + ((d1 == -1) ? cA1 : 0.f);
        const float A1 = (keep1 ? cA1 : 0.f)
                       + ((d0 == 1) ? cA0 : 0.f)
                       + ((hasR && dR == -1) ? cAR : 0.f);

        *(float4*)(ro + (size_t)(k0 << 1)) = make_float4(A0, cD0, A1, cD1);
    }
}

extern "C" void kernel_launch(void* const* d_in, const int* in_sizes, int n_in,
                              void* d_out, int out_size, void* d_ws, size_t ws_size,
                              hipStream_t stream) {
    const float* x = (const float*)d_in[0];
    float* out = (float*)d_out;
    dim3 block(256);
    dim3 grid(2048);  // 256 CU x 8 blocks/CU; grid-stride covers 8388608 chunks
    hipLaunchKernelGGL(sst_kernel, grid, block, 0, stream, x, out);
}